// Round 1
// baseline (336.394 us; speedup 1.0000x reference)
//
#include <hip/hip_runtime.h>
#include <hip/hip_bf16.h>
#include <cstdint>
#include <cstddef>

// Problem constants
#define Bq  4
#define Nq  2048
#define Mq  256
#define Dq  1024
#define CDq 768
#define Hq  8
#define DHq 64
#define Jq  2305   // Mq + 1 + Nq

typedef __bf16  bf16x8 __attribute__((ext_vector_type(8)));
typedef float   f32x4  __attribute__((ext_vector_type(4)));
typedef short   s16x8  __attribute__((ext_vector_type(8)));
typedef unsigned short u16;

__device__ __forceinline__ u16 f2b(float v) {          // f32 -> bf16 (RNE)
  unsigned x = __builtin_bit_cast(unsigned, v);
  unsigned r = (x + 0x7fffu + ((x >> 16) & 1u)) >> 16;
  return (u16)r;
}
__device__ __forceinline__ float b2f(u16 u) {
  unsigned x = ((unsigned)u) << 16;
  return __builtin_bit_cast(float, x);
}
__device__ __forceinline__ f32x4 mfma16(bf16x8 a, bf16x8 b, f32x4 c) {
  return __builtin_amdgcn_mfma_f32_16x16x32_bf16(a, b, c, 0, 0, 0);
}
__device__ __forceinline__ bf16x8 frag_ld(const u16* p) {
  return __builtin_bit_cast(bf16x8, *(const s16x8*)p);
}
__device__ __forceinline__ void stout(float* p, float v) { *p = v; }
__device__ __forceinline__ void stout(u16*   p, float v) { *p = f2b(v); }

// ---------------- LayerNorm (fp32 in, OT out) ----------------
template <typename OT>
__global__ __launch_bounds__(256) void ln_kernel(const float* __restrict__ in,
                                                 const float* __restrict__ g,
                                                 const float* __restrict__ bb,
                                                 OT* __restrict__ out, int D) {
  const int row = blockIdx.x;
  const int tid = threadIdx.x;
  __shared__ float buf[1024];
  __shared__ float red[8];
  const float* x = in + (size_t)row * D;
  float s = 0.f, s2 = 0.f;
  for (int i = tid; i < D; i += 256) {
    float v = x[i];
    buf[i] = v;
    s += v; s2 += v * v;
  }
  #pragma unroll
  for (int off = 32; off; off >>= 1) {
    s  += __shfl_down(s,  off);
    s2 += __shfl_down(s2, off);
  }
  if ((tid & 63) == 0) { red[tid >> 6] = s; red[4 + (tid >> 6)] = s2; }
  __syncthreads();
  float sum = red[0] + red[1] + red[2] + red[3];
  float sq  = red[4] + red[5] + red[6] + red[7];
  float mean = sum / D;
  float var  = sq / D - mean * mean;
  float rstd = rsqrtf(var + 1e-5f);
  for (int i = tid; i < D; i += 256)
    stout(out + (size_t)row * D + i, (buf[i] - mean) * rstd * g[i] + bb[i]);
}

// ---------------- weight transpose: WT[n][k] = bf16(W[k][n]) ----------------
__global__ void wtrans(const float* __restrict__ W, u16* __restrict__ WT,
                       int K, int N) {
  int idx = blockIdx.x * 256 + threadIdx.x;
  if (idx >= K * N) return;
  int n = idx % N, k = idx / N;
  WT[(size_t)n * K + k] = f2b(W[idx]);
}

// ---------------- GEMM: C(MxN) = A(MxK,bf16) @ B, B given as BT(NxK,bf16) ----
// 64x64 tile, BK=32, 4 waves (each 32x32 = 2x2 fragments of 16x16x32 MFMA)
template <typename OT>
__global__ __launch_bounds__(256) void gemm_bf16(const u16* __restrict__ A,
                                                 const u16* __restrict__ BT,
                                                 OT* __restrict__ C,
                                                 int M, int N, int K) {
  __shared__ __align__(16) u16 Al[64][40];   // +8 pad: bank-spread
  __shared__ __align__(16) u16 Bl[64][40];
  const int tid  = threadIdx.x;
  const int lane = tid & 63, wave = tid >> 6;
  const int l16  = lane & 15, lhi = lane >> 4;
  const int m0 = blockIdx.x * 64, n0 = blockIdx.y * 64;
  const int wm = (wave >> 1) * 32, wn = (wave & 1) * 32;
  const int sr = tid >> 2, sc = (tid & 3) * 8;
  f32x4 acc[2][2];
  #pragma unroll
  for (int i = 0; i < 2; ++i)
    #pragma unroll
    for (int j = 0; j < 2; ++j) acc[i][j] = f32x4{0.f, 0.f, 0.f, 0.f};

  for (int k0 = 0; k0 < K; k0 += 32) {
    __syncthreads();
    *(s16x8*)&Al[sr][sc] = *(const s16x8*)(A  + (size_t)(m0 + sr) * K + k0 + sc);
    *(s16x8*)&Bl[sr][sc] = *(const s16x8*)(BT + (size_t)(n0 + sr) * K + k0 + sc);
    __syncthreads();
    bf16x8 af[2], bfr[2];
    #pragma unroll
    for (int mt = 0; mt < 2; ++mt) af[mt]  = frag_ld(&Al[wm + mt * 16 + l16][lhi * 8]);
    #pragma unroll
    for (int nt = 0; nt < 2; ++nt) bfr[nt] = frag_ld(&Bl[wn + nt * 16 + l16][lhi * 8]);
    #pragma unroll
    for (int mt = 0; mt < 2; ++mt)
      #pragma unroll
      for (int nt = 0; nt < 2; ++nt)
        acc[mt][nt] = mfma16(af[mt], bfr[nt], acc[mt][nt]);
  }
  #pragma unroll
  for (int mt = 0; mt < 2; ++mt)
    #pragma unroll
    for (int nt = 0; nt < 2; ++nt)
      #pragma unroll
      for (int r = 0; r < 4; ++r)
        stout(C + (size_t)(m0 + wm + mt * 16 + lhi * 4 + r) * N
                + (n0 + wn + nt * 16 + l16),
              acc[mt][nt][r]);
}

// ---------------- build concatenated K/V (B,J,64) bf16 ----------------
__global__ void build_kv(const u16* __restrict__ kvb,   // (B*N,128) bf16
                         const u16* __restrict__ ckvb,  // (B*M,128) bf16
                         const float* __restrict__ nullkv, // (2,64) f32
                         const float* __restrict__ bc,     // (128,) f32
                         u16* __restrict__ Kg, u16* __restrict__ Vg) {
  int idx = blockIdx.x * 256 + threadIdx.x;
  if (idx >= Bq * Jq * 64) return;
  int d = idx & 63;
  int t = idx >> 6;
  int j = t % Jq;
  int b = t / Jq;
  float k, v;
  if (j < Mq) {
    const u16* p = ckvb + (size_t)(b * Mq + j) * 128;
    k = b2f(p[d])      + bc[d];
    v = b2f(p[64 + d]) + bc[64 + d];
  } else if (j == Mq) {
    k = nullkv[d];
    v = nullkv[64 + d];
  } else {
    const u16* p = kvb + (size_t)(b * Nq + (j - Mq - 1)) * 128;
    k = b2f(p[d]);
    v = b2f(p[64 + d]);
  }
  Kg[idx] = f2b(k);
  Vg[idx] = f2b(v);
}

// ---------------- attention ----------------
// grid (N/64, H, B), block 256 = 4 waves; wave w owns 16 q-rows.
// Per 64-wide J chunk: stage K(64x64) + V^T(64x64) in LDS, S=q@K^T*scale+bias,
// online softmax (16-lane shfl groups), P->LDS, PV MFMA.
__global__ __launch_bounds__(256) void attn_kernel(const u16* __restrict__ qb,
                                                   const u16* __restrict__ Kg,
                                                   const u16* __restrict__ Vg,
                                                   const float* __restrict__ bias,
                                                   u16* __restrict__ att) {
  __shared__ __align__(16) u16 Kl [64][72];   // row pad +8 -> bank spread
  __shared__ __align__(16) u16 VTl[64][72];
  __shared__ __align__(16) u16 Pl [4][16][72];
  const int tid  = threadIdx.x;
  const int wave = tid >> 6, lane = tid & 63;
  const int l16  = lane & 15, lhi = lane >> 4;
  const int qt = blockIdx.x, h = blockIdx.y, b = blockIdx.z;
  const int qrow0 = qt * 64 + wave * 16;

  // hoist q fragments (A-operand layout: row=l16, k = dk*32 + lhi*8 + j)
  bf16x8 qf[2];
  {
    const u16* qp = qb + ((size_t)(b * Nq + qrow0 + l16)) * (Hq * DHq)
                       + h * DHq + lhi * 8;
    qf[0] = frag_ld(qp);
    qf[1] = frag_ld(qp + 32);
  }

  float m_r[4], l_r[4];
  f32x4 oacc[4];
  #pragma unroll
  for (int r = 0; r < 4; ++r) { m_r[r] = -INFINITY; l_r[r] = 0.f; }
  #pragma unroll
  for (int dt = 0; dt < 4; ++dt) oacc[dt] = f32x4{0.f, 0.f, 0.f, 0.f};

  const float* biasBase = bias + ((size_t)(b * Hq + h)) * Nq * (size_t)Jq;

  const int sr = tid >> 2;            // staging row (j-local), 0..63
  const int scb = (tid & 3) * 16;     // staging col base (d), 0/16/32/48

  for (int jc = 0; jc < Jq; jc += 64) {
    __syncthreads();
    {
      int j = jc + sr;
      s16x8 k0, k1, v0, v1;
      if (j < Jq) {
        const s16x8* kp = (const s16x8*)(Kg + ((size_t)(b * Jq + j)) * 64 + scb);
        const s16x8* vp = (const s16x8*)(Vg + ((size_t)(b * Jq + j)) * 64 + scb);
        k0 = kp[0]; k1 = kp[1]; v0 = vp[0]; v1 = vp[1];
      } else {
        k0 = s16x8{0,0,0,0,0,0,0,0}; k1 = k0; v0 = k0; v1 = k0;
      }
      *(s16x8*)&Kl[sr][scb]     = k0;
      *(s16x8*)&Kl[sr][scb + 8] = k1;
      #pragma unroll
      for (int i = 0; i < 8; ++i) {
        VTl[scb + i][sr]     = (u16)v0[i];
        VTl[scb + 8 + i][sr] = (u16)v1[i];
      }
    }
    __syncthreads();

    // ---- S = q @ K^T, scale, + bias ----
    float sv[4][4];
    #pragma unroll
    for (int jt = 0; jt < 4; ++jt) {
      f32x4 s = f32x4{0.f, 0.f, 0.f, 0.f};
      s = mfma16(qf[0], frag_ld(&Kl[jt * 16 + l16][lhi * 8]),      s);
      s = mfma16(qf[1], frag_ld(&Kl[jt * 16 + l16][32 + lhi * 8]), s);
      int jg = jc + jt * 16 + l16;
      #pragma unroll
      for (int r = 0; r < 4; ++r) {
        float bb = (jg < Jq)
            ? biasBase[(size_t)(qrow0 + lhi * 4 + r) * Jq + jg]
            : -1e30f;
        sv[jt][r] = s[r] * 0.125f + bb;
      }
    }

    // ---- online softmax over this 64-wide chunk ----
    #pragma unroll
    for (int r = 0; r < 4; ++r) {
      float mx = fmaxf(fmaxf(sv[0][r], sv[1][r]), fmaxf(sv[2][r], sv[3][r]));
      #pragma unroll
      for (int off = 1; off < 16; off <<= 1) mx = fmaxf(mx, __shfl_xor(mx, off));
      float mnew = fmaxf(m_r[r], mx);
      float corr = __expf(m_r[r] - mnew);   // exp(-inf)=0 on first chunk
      float ps = 0.f;
      #pragma unroll
      for (int jt = 0; jt < 4; ++jt) {
        float p = __expf(sv[jt][r] - mnew);
        sv[jt][r] = p;
        ps += p;
      }
      #pragma unroll
      for (int off = 1; off < 16; off <<= 1) ps += __shfl_xor(ps, off);
      l_r[r] = l_r[r] * corr + ps;
      m_r[r] = mnew;
      #pragma unroll
      for (int dt = 0; dt < 4; ++dt) oacc[dt][r] *= corr;
    }

    // ---- P -> LDS (D-layout scatter), then PV ----
    #pragma unroll
    for (int r = 0; r < 4; ++r)
      #pragma unroll
      for (int jt = 0; jt < 4; ++jt)
        Pl[wave][lhi * 4 + r][jt * 16 + l16] = f2b(sv[jt][r]);

    #pragma unroll
    for (int jk = 0; jk < 2; ++jk) {
      bf16x8 pf = frag_ld(&Pl[wave][l16][jk * 32 + lhi * 8]);
      #pragma unroll
      for (int dt = 0; dt < 4; ++dt) {
        bf16x8 vf = frag_ld(&VTl[dt * 16 + l16][jk * 32 + lhi * 8]);
        oacc[dt] = mfma16(pf, vf, oacc[dt]);
      }
    }
  }

  // ---- epilogue: normalize and store att (B,N,H*DH) bf16 ----
  #pragma unroll
  for (int r = 0; r < 4; ++r) {
    float inv = 1.0f / l_r[r];
    int row = qrow0 + lhi * 4 + r;
    u16* op = att + ((size_t)(b * Nq + row)) * (Hq * DHq) + h * DHq;
    #pragma unroll
    for (int dt = 0; dt < 4; ++dt)
      op[dt * 16 + l16] = f2b(oacc[dt][r] * inv);
  }
}

// ---------------- host ----------------
extern "C" void kernel_launch(void* const* d_in, const int* in_sizes, int n_in,
                              void* d_out, int out_size, void* d_ws, size_t ws_size,
                              hipStream_t stream) {
  const float* x       = (const float*)d_in[0];
  const float* context = (const float*)d_in[1];
  const float* att_bias= (const float*)d_in[2];
  const float* ln_g    = (const float*)d_in[3];
  const float* ln_b    = (const float*)d_in[4];
  const float* null_kv = (const float*)d_in[5];
  const float* Wq      = (const float*)d_in[6];
  const float* Wkv     = (const float*)d_in[7];
  const float* cln_g   = (const float*)d_in[8];
  const float* cln_b   = (const float*)d_in[9];
  const float* Wc      = (const float*)d_in[10];
  const float* bc      = (const float*)d_in[11];
  const float* Wo      = (const float*)d_in[12];
  const float* oln_g   = (const float*)d_in[13];
  const float* oln_b   = (const float*)d_in[14];
  float* out = (float*)d_out;

  char* p = (char*)d_ws;
  auto alloc = [&](size_t bytes) {
    void* r = (void*)p;
    p += (bytes + 255) & ~(size_t)255;
    return r;
  };
  u16* xn    = (u16*)alloc((size_t)Bq * Nq * Dq * 2);
  u16* ctxn  = (u16*)alloc((size_t)Bq * Mq * CDq * 2);
  u16* WqT   = (u16*)alloc((size_t)Dq * Hq * DHq * 2);
  u16* WkvT  = (u16*)alloc((size_t)Dq * 2 * DHq * 2);
  u16* WcT   = (u16*)alloc((size_t)CDq * 2 * DHq * 2);
  u16* WoT   = (u16*)alloc((size_t)Hq * DHq * Dq * 2);
  u16* qbuf  = (u16*)alloc((size_t)Bq * Nq * Hq * DHq * 2);
  u16* kvb   = (u16*)alloc((size_t)Bq * Nq * 2 * DHq * 2);
  u16* ckvb  = (u16*)alloc((size_t)Bq * Mq * 2 * DHq * 2);
  u16* Kgl   = (u16*)alloc((size_t)Bq * Jq * DHq * 2);
  u16* Vgl   = (u16*)alloc((size_t)Bq * Jq * DHq * 2);
  u16* attb  = (u16*)alloc((size_t)Bq * Nq * Hq * DHq * 2);
  float* y   = (float*)alloc((size_t)Bq * Nq * Dq * 4);

  // 1. LayerNorms -> bf16
  ln_kernel<u16><<<Bq * Nq, 256, 0, stream>>>(x, ln_g, ln_b, xn, Dq);
  ln_kernel<u16><<<Bq * Mq, 256, 0, stream>>>(context, cln_g, cln_b, ctxn, CDq);

  // 2. weight transposes -> bf16
  wtrans<<<(Dq * Hq * DHq + 255) / 256, 256, 0, stream>>>(Wq, WqT, Dq, Hq * DHq);
  wtrans<<<(Dq * 2 * DHq + 255) / 256, 256, 0, stream>>>(Wkv, WkvT, Dq, 2 * DHq);
  wtrans<<<(CDq * 2 * DHq + 255) / 256, 256, 0, stream>>>(Wc, WcT, CDq, 2 * DHq);
  wtrans<<<(Hq * DHq * Dq + 255) / 256, 256, 0, stream>>>(Wo, WoT, Hq * DHq, Dq);

  // 3. projections (bf16 out; q unscaled -- scale applied in attention)
  gemm_bf16<u16><<<dim3(Bq * Nq / 64, (Hq * DHq) / 64), 256, 0, stream>>>(
      xn, WqT, qbuf, Bq * Nq, Hq * DHq, Dq);
  gemm_bf16<u16><<<dim3(Bq * Nq / 64, (2 * DHq) / 64), 256, 0, stream>>>(
      xn, WkvT, kvb, Bq * Nq, 2 * DHq, Dq);
  gemm_bf16<u16><<<dim3(Bq * Mq / 64, (2 * DHq) / 64), 256, 0, stream>>>(
      ctxn, WcT, ckvb, Bq * Mq, 2 * DHq, CDq);

  // 4. concat K/V
  build_kv<<<(Bq * Jq * 64 + 255) / 256, 256, 0, stream>>>(
      kvb, ckvb, null_kv, bc, Kgl, Vgl);

  // 5. attention
  attn_kernel<<<dim3(Nq / 64, Hq, Bq), 256, 0, stream>>>(
      qbuf, Kgl, Vgl, att_bias, attb);

  // 6. output projection (f32) + final LN
  gemm_bf16<float><<<dim3(Bq * Nq / 64, Dq / 64), 256, 0, stream>>>(
      attb, WoT, y, Bq * Nq, Dq, Hq * DHq);
  ln_kernel<float><<<Bq * Nq, 256, 0, stream>>>(y, oln_g, oln_b, out, Dq);
}

// Round 2
// 323.769 us; speedup vs baseline: 1.0390x; 1.0390x over previous
//
#include <hip/hip_runtime.h>
#include <hip/hip_bf16.h>
#include <cstdint>
#include <cstddef>

// Problem constants
#define Bq  4
#define Nq  2048
#define Mq  256
#define Dq  1024
#define CDq 768
#define Hq  8
#define DHq 64
#define Jq  2305   // Mq + 1 + Nq
#define QKVN 640   // H*DH + 2*DH (fused q+kv projection width)

typedef __bf16  bf16x8 __attribute__((ext_vector_type(8)));
typedef float   f32x4  __attribute__((ext_vector_type(4)));
typedef short   s16x8  __attribute__((ext_vector_type(8)));
typedef unsigned short u16;

__device__ __forceinline__ u16 f2b(float v) {          // f32 -> bf16 (RNE)
  unsigned x = __builtin_bit_cast(unsigned, v);
  unsigned r = (x + 0x7fffu + ((x >> 16) & 1u)) >> 16;
  return (u16)r;
}
__device__ __forceinline__ float b2f(u16 u) {
  unsigned x = ((unsigned)u) << 16;
  return __builtin_bit_cast(float, x);
}
__device__ __forceinline__ f32x4 mfma16(bf16x8 a, bf16x8 b, f32x4 c) {
  return __builtin_amdgcn_mfma_f32_16x16x32_bf16(a, b, c, 0, 0, 0);
}
__device__ __forceinline__ bf16x8 frag_ld(const u16* p) {
  return __builtin_bit_cast(bf16x8, *(const s16x8*)p);
}
__device__ __forceinline__ void stout(float* p, float v) { *p = v; }
__device__ __forceinline__ void stout(u16*   p, float v) { *p = f2b(v); }

// async global->LDS, 16B per lane. ldsDst must be the wave-uniform base
// (HW adds lane*16); gSrc is per-lane.
__device__ __forceinline__ void gl_lds16(const void* gSrc, void* ldsDst) {
  __builtin_amdgcn_global_load_lds(
      (const __attribute__((address_space(1))) void*)gSrc,
      (__attribute__((address_space(3))) void*)ldsDst, 16, 0, 0);
}

// ---------------- LayerNorm (fp32 in, OT out) ----------------
template <typename OT>
__global__ __launch_bounds__(256) void ln_kernel(const float* __restrict__ in,
                                                 const float* __restrict__ g,
                                                 const float* __restrict__ bb,
                                                 OT* __restrict__ out, int D) {
  const int row = blockIdx.x;
  const int tid = threadIdx.x;
  __shared__ float buf[1024];
  __shared__ float red[8];
  const float* x = in + (size_t)row * D;
  float s = 0.f, s2 = 0.f;
  for (int i = tid; i < D; i += 256) {
    float v = x[i];
    buf[i] = v;
    s += v; s2 += v * v;
  }
  #pragma unroll
  for (int off = 32; off; off >>= 1) {
    s  += __shfl_down(s,  off);
    s2 += __shfl_down(s2, off);
  }
  if ((tid & 63) == 0) { red[tid >> 6] = s; red[4 + (tid >> 6)] = s2; }
  __syncthreads();
  float sum = red[0] + red[1] + red[2] + red[3];
  float sq  = red[4] + red[5] + red[6] + red[7];
  float mean = sum / D;
  float var  = sq / D - mean * mean;
  float rstd = rsqrtf(var + 1e-5f);
  for (int i = tid; i < D; i += 256)
    stout(out + (size_t)row * D + i, (buf[i] - mean) * rstd * g[i] + bb[i]);
}

// ------------- tiled weight transpose: WT[n][k] = bf16(W[k][n]) -------------
// grid (N/32, K/32), block 256. Coalesced read AND write via 32x33 LDS tile.
__global__ __launch_bounds__(256) void wtrans32(const float* __restrict__ W,
                                                u16* __restrict__ WT,
                                                int K, int N) {
  __shared__ float T[32][33];
  const int n0 = blockIdx.x * 32, k0 = blockIdx.y * 32;
  const int tx = threadIdx.x & 31, ty = threadIdx.x >> 5;   // ty 0..7
  #pragma unroll
  for (int i = 0; i < 32; i += 8)
    T[ty + i][tx] = W[(size_t)(k0 + ty + i) * N + n0 + tx];
  __syncthreads();
  #pragma unroll
  for (int i = 0; i < 32; i += 8)
    WT[(size_t)(n0 + ty + i) * K + k0 + tx] = f2b(T[tx][ty + i]);
}

// --------- GEMM (m97 structure): C(MxN) = A(MxK,bf16) @ BT(NxK,bf16)^T ------
// 128x128 tile, BK=32, 256 thr = 4 waves (2x2), each wave 64x64 = 4x4 frags.
// Staging via global_load_lds width 16 into LINEAR row-major LDS [128][32].
template <typename OT>
__global__ __launch_bounds__(256) void gemm128(const u16* __restrict__ A,
                                               const u16* __restrict__ BT,
                                               OT* __restrict__ C,
                                               int M, int N, int K) {
  __shared__ __align__(16) u16 Al[128 * 32];
  __shared__ __align__(16) u16 Bl[128 * 32];
  const int tid  = threadIdx.x;
  const int lane = tid & 63, wave = tid >> 6;
  const int l16  = lane & 15, lhi = lane >> 4;
  const int m0 = blockIdx.x * 128, n0 = blockIdx.y * 128;
  const int wm = (wave >> 1) * 64, wn = (wave & 1) * 64;

  // staging geometry: per 4KB group, this wave covers bytes
  // [wave*1024 + lane*16, +16). Row = 64B of bf16 (32 elems).
  const int offB = (wave << 10) + (lane << 4);  // byte offset in 4KB group
  const int srow = offB >> 6;                   // 0..63
  const int scby = offB & 63;                   // byte col within row

  f32x4 acc[4][4];
  #pragma unroll
  for (int i = 0; i < 4; ++i)
    #pragma unroll
    for (int j = 0; j < 4; ++j) acc[i][j] = f32x4{0.f, 0.f, 0.f, 0.f};

  for (int k0 = 0; k0 < K; k0 += 32) {
    __syncthreads();
    #pragma unroll
    for (int c = 0; c < 2; ++c) {
      gl_lds16((const char*)(A  + (size_t)(m0 + srow + c * 64) * K + k0) + scby,
               (char*)Al + c * 4096 + (wave << 10));
      gl_lds16((const char*)(BT + (size_t)(n0 + srow + c * 64) * K + k0) + scby,
               (char*)Bl + c * 4096 + (wave << 10));
    }
    __syncthreads();   // compiler inserts s_waitcnt vmcnt(0) before barrier

    bf16x8 af[4], bfr[4];
    #pragma unroll
    for (int mt = 0; mt < 4; ++mt)
      af[mt] = frag_ld(Al + (wm + mt * 16 + l16) * 32 + lhi * 8);
    #pragma unroll
    for (int nt = 0; nt < 4; ++nt)
      bfr[nt] = frag_ld(Bl + (wn + nt * 16 + l16) * 32 + lhi * 8);
    #pragma unroll
    for (int mt = 0; mt < 4; ++mt)
      #pragma unroll
      for (int nt = 0; nt < 4; ++nt)
        acc[mt][nt] = mfma16(af[mt], bfr[nt], acc[mt][nt]);
  }

  #pragma unroll
  for (int mt = 0; mt < 4; ++mt)
    #pragma unroll
    for (int nt = 0; nt < 4; ++nt)
      #pragma unroll
      for (int r = 0; r < 4; ++r)
        stout(C + (size_t)(m0 + wm + mt * 16 + lhi * 4 + r) * N
                + (n0 + wn + nt * 16 + l16),
              acc[mt][nt][r]);
}

// ---------------- build concatenated K/V (B,J,64) bf16 ----------------
// kv now lives in the fused qkv buffer: row stride QKVN, cols 512..639.
__global__ void build_kv(const u16* __restrict__ qkv,   // (B*N,640) bf16
                         const u16* __restrict__ ckvb,  // (B*M,128) bf16
                         const float* __restrict__ nullkv, // (2,64) f32
                         const float* __restrict__ bc,     // (128,) f32
                         u16* __restrict__ Kg, u16* __restrict__ Vg) {
  int idx = blockIdx.x * 256 + threadIdx.x;
  if (idx >= Bq * Jq * 64) return;
  int d = idx & 63;
  int t = idx >> 6;
  int j = t % Jq;
  int b = t / Jq;
  float k, v;
  if (j < Mq) {
    const u16* p = ckvb + (size_t)(b * Mq + j) * 128;
    k = b2f(p[d])      + bc[d];
    v = b2f(p[64 + d]) + bc[64 + d];
  } else if (j == Mq) {
    k = nullkv[d];
    v = nullkv[64 + d];
  } else {
    const u16* p = qkv + (size_t)(b * Nq + (j - Mq - 1)) * QKVN + 512;
    k = b2f(p[d]);
    v = b2f(p[64 + d]);
  }
  Kg[idx] = f2b(k);
  Vg[idx] = f2b(v);
}

// ---------------- attention ----------------
// grid (N/64, H, B), block 256 = 4 waves; wave w owns 16 q-rows.
__global__ __launch_bounds__(256) void attn_kernel(const u16* __restrict__ qkv,
                                                   const u16* __restrict__ Kg,
                                                   const u16* __restrict__ Vg,
                                                   const float* __restrict__ bias,
                                                   u16* __restrict__ att) {
  __shared__ __align__(16) u16 Kl [64][72];   // row pad +8 -> bank spread
  __shared__ __align__(16) u16 VTl[64][72];
  __shared__ __align__(16) u16 Pl [4][16][72];
  const int tid  = threadIdx.x;
  const int wave = tid >> 6, lane = tid & 63;
  const int l16  = lane & 15, lhi = lane >> 4;
  const int qt = blockIdx.x, h = blockIdx.y, b = blockIdx.z;
  const int qrow0 = qt * 64 + wave * 16;

  bf16x8 qf[2];
  {
    const u16* qp = qkv + ((size_t)(b * Nq + qrow0 + l16)) * QKVN
                        + h * DHq + lhi * 8;
    qf[0] = frag_ld(qp);
    qf[1] = frag_ld(qp + 32);
  }

  float m_r[4], l_r[4];
  f32x4 oacc[4];
  #pragma unroll
  for (int r = 0; r < 4; ++r) { m_r[r] = -INFINITY; l_r[r] = 0.f; }
  #pragma unroll
  for (int dt = 0; dt < 4; ++dt) oacc[dt] = f32x4{0.f, 0.f, 0.f, 0.f};

  const float* biasBase = bias + ((size_t)(b * Hq + h)) * Nq * (size_t)Jq;

  const int sr = tid >> 2;            // staging row (j-local), 0..63
  const int scb = (tid & 3) * 16;     // staging col base (d)

  for (int jc = 0; jc < Jq; jc += 64) {
    __syncthreads();
    {
      int j = jc + sr;
      s16x8 k0, k1, v0, v1;
      if (j < Jq) {
        const s16x8* kp = (const s16x8*)(Kg + ((size_t)(b * Jq + j)) * 64 + scb);
        const s16x8* vp = (const s16x8*)(Vg + ((size_t)(b * Jq + j)) * 64 + scb);
        k0 = kp[0]; k1 = kp[1]; v0 = vp[0]; v1 = vp[1];
      } else {
        k0 = s16x8{0,0,0,0,0,0,0,0}; k1 = k0; v0 = k0; v1 = k0;
      }
      *(s16x8*)&Kl[sr][scb]     = k0;
      *(s16x8*)&Kl[sr][scb + 8] = k1;
      #pragma unroll
      for (int i = 0; i < 8; ++i) {
        VTl[scb + i][sr]     = (u16)v0[i];
        VTl[scb + 8 + i][sr] = (u16)v1[i];
      }
    }
    __syncthreads();

    // ---- S = q @ K^T, scale, + bias ----
    float sv[4][4];
    #pragma unroll
    for (int jt = 0; jt < 4; ++jt) {
      f32x4 s = f32x4{0.f, 0.f, 0.f, 0.f};
      s = mfma16(qf[0], frag_ld(&Kl[jt * 16 + l16][lhi * 8]),      s);
      s = mfma16(qf[1], frag_ld(&Kl[jt * 16 + l16][32 + lhi * 8]), s);
      int jg = jc + jt * 16 + l16;
      #pragma unroll
      for (int r = 0; r < 4; ++r) {
        float bb = (jg < Jq)
            ? biasBase[(size_t)(qrow0 + lhi * 4 + r) * Jq + jg]
            : -1e30f;
        sv[jt][r] = s[r] * 0.125f + bb;
      }
    }

    // ---- online softmax over this 64-wide chunk ----
    #pragma unroll
    for (int r = 0; r < 4; ++r) {
      float mx = fmaxf(fmaxf(sv[0][r], sv[1][r]), fmaxf(sv[2][r], sv[3][r]));
      #pragma unroll
      for (int off = 1; off < 16; off <<= 1) mx = fmaxf(mx, __shfl_xor(mx, off));
      float mnew = fmaxf(m_r[r], mx);
      float corr = __expf(m_r[r] - mnew);
      float ps = 0.f;
      #pragma unroll
      for (int jt = 0; jt < 4; ++jt) {
        float p = __expf(sv[jt][r] - mnew);
        sv[jt][r] = p;
        ps += p;
      }
      #pragma unroll
      for (int off = 1; off < 16; off <<= 1) ps += __shfl_xor(ps, off);
      l_r[r] = l_r[r] * corr + ps;
      m_r[r] = mnew;
      #pragma unroll
      for (int dt = 0; dt < 4; ++dt) oacc[dt][r] *= corr;
    }

    // ---- P -> LDS, then PV ----
    #pragma unroll
    for (int r = 0; r < 4; ++r)
      #pragma unroll
      for (int jt = 0; jt < 4; ++jt)
        Pl[wave][lhi * 4 + r][jt * 16 + l16] = f2b(sv[jt][r]);

    #pragma unroll
    for (int jk = 0; jk < 2; ++jk) {
      bf16x8 pf = frag_ld(&Pl[wave][l16][jk * 32 + lhi * 8]);
      #pragma unroll
      for (int dt = 0; dt < 4; ++dt) {
        bf16x8 vf = frag_ld(&VTl[dt * 16 + l16][jk * 32 + lhi * 8]);
        oacc[dt] = mfma16(pf, vf, oacc[dt]);
      }
    }
  }

  #pragma unroll
  for (int r = 0; r < 4; ++r) {
    float inv = 1.0f / l_r[r];
    int row = qrow0 + lhi * 4 + r;
    u16* op = att + ((size_t)(b * Nq + row)) * (Hq * DHq) + h * DHq;
    #pragma unroll
    for (int dt = 0; dt < 4; ++dt)
      op[dt * 16 + l16] = f2b(oacc[dt][r] * inv);
  }
}

// ---------------- host ----------------
extern "C" void kernel_launch(void* const* d_in, const int* in_sizes, int n_in,
                              void* d_out, int out_size, void* d_ws, size_t ws_size,
                              hipStream_t stream) {
  const float* x       = (const float*)d_in[0];
  const float* context = (const float*)d_in[1];
  const float* att_bias= (const float*)d_in[2];
  const float* ln_g    = (const float*)d_in[3];
  const float* ln_b    = (const float*)d_in[4];
  const float* null_kv = (const float*)d_in[5];
  const float* Wq      = (const float*)d_in[6];
  const float* Wkv     = (const float*)d_in[7];
  const float* cln_g   = (const float*)d_in[8];
  const float* cln_b   = (const float*)d_in[9];
  const float* Wc      = (const float*)d_in[10];
  const float* bc      = (const float*)d_in[11];
  const float* Wo      = (const float*)d_in[12];
  const float* oln_g   = (const float*)d_in[13];
  const float* oln_b   = (const float*)d_in[14];
  float* out = (float*)d_out;

  char* p = (char*)d_ws;
  auto alloc = [&](size_t bytes) {
    void* r = (void*)p;
    p += (bytes + 255) & ~(size_t)255;
    return r;
  };
  u16* xn     = (u16*)alloc((size_t)Bq * Nq * Dq * 2);
  u16* ctxn   = (u16*)alloc((size_t)Bq * Mq * CDq * 2);
  u16* WqkvT  = (u16*)alloc((size_t)QKVN * Dq * 2);       // [640][1024]
  u16* WcT    = (u16*)alloc((size_t)2 * DHq * CDq * 2);   // [128][768]
  u16* WoT    = (u16*)alloc((size_t)Dq * Hq * DHq * 2);   // [1024][512]
  u16* qkv    = (u16*)alloc((size_t)Bq * Nq * QKVN * 2);  // fused q|kv
  u16* ckvb   = (u16*)alloc((size_t)Bq * Mq * 2 * DHq * 2);
  u16* Kgl    = (u16*)alloc((size_t)Bq * Jq * DHq * 2);
  u16* Vgl    = (u16*)alloc((size_t)Bq * Jq * DHq * 2);
  u16* attb   = (u16*)alloc((size_t)Bq * Nq * Hq * DHq * 2);
  float* y    = (float*)alloc((size_t)Bq * Nq * Dq * 4);

  // 1. LayerNorms -> bf16
  ln_kernel<u16><<<Bq * Nq, 256, 0, stream>>>(x, ln_g, ln_b, xn, Dq);
  ln_kernel<u16><<<Bq * Mq, 256, 0, stream>>>(context, cln_g, cln_b, ctxn, CDq);

  // 2. weight transposes -> bf16 (tiled, coalesced both sides)
  wtrans32<<<dim3(512 / 32, Dq / 32), 256, 0, stream>>>(Wq, WqkvT, Dq, 512);
  wtrans32<<<dim3(128 / 32, Dq / 32), 256, 0, stream>>>(Wkv, WqkvT + (size_t)512 * Dq, Dq, 128);
  wtrans32<<<dim3(128 / 32, CDq / 32), 256, 0, stream>>>(Wc, WcT, CDq, 128);
  wtrans32<<<dim3(Dq / 32, 512 / 32), 256, 0, stream>>>(Wo, WoT, 512, Dq);

  // 3. projections (fused q|kv), context kv
  gemm128<u16><<<dim3(Bq * Nq / 128, QKVN / 128), 256, 0, stream>>>(
      xn, WqkvT, qkv, Bq * Nq, QKVN, Dq);
  gemm128<u16><<<dim3(Bq * Mq / 128, 128 / 128), 256, 0, stream>>>(
      ctxn, WcT, ckvb, Bq * Mq, 2 * DHq, CDq);

  // 4. concat K/V
  build_kv<<<(Bq * Jq * 64 + 255) / 256, 256, 0, stream>>>(
      qkv, ckvb, null_kv, bc, Kgl, Vgl);

  // 5. attention
  attn_kernel<<<dim3(Nq / 64, Hq, Bq), 256, 0, stream>>>(
      qkv, Kgl, Vgl, att_bias, attb);

  // 6. output projection (f32) + final LN
  gemm128<float><<<dim3(Bq * Nq / 128, Dq / 128), 256, 0, stream>>>(
      attb, WoT, y, Bq * Nq, Dq, Hq * DHq);
  ln_kernel<float><<<Bq * Nq, 256, 0, stream>>>(y, oln_g, oln_b, out, Dq);
}